// Round 1
// baseline (727.332 us; speedup 1.0000x reference)
//
#include <hip/hip_runtime.h>

#define B_DIM 256
#define H_DIM 4608
#define K_X   512
#define K_TOT 5120
#define KT    32
#define NSTEP (K_TOT / KT)   // 160
#define LDA   40             // padded LDS row stride in bf16 elements (80B: conflict-free for b128 ops)

typedef __attribute__((ext_vector_type(8))) short  short8;   // 8 x bf16 (4 VGPRs) - MFMA A/B frag
typedef __attribute__((ext_vector_type(4))) float  floatx4;  // MFMA C/D frag

// fp32 -> bf16 (round-half-up) pair pack: low half = a, high half = b
static __device__ __forceinline__ unsigned pkbf(float a, float b){
  unsigned ua = (__float_as_uint(a) + 0x8000u) >> 16;
  unsigned ub = (__float_as_uint(b) + 0x8000u) & 0xFFFF0000u;
  return ua | ub;
}

static __device__ __forceinline__ float sigm(float v){
  return 1.0f / (1.0f + __expf(-v));
}
static __device__ __forceinline__ float tanh_fast(float v){
  float ax = fabsf(v);
  float e  = __expf(-2.0f * ax);
  float t  = (1.0f - e) / (1.0f + e);
  return copysignf(t, v);
}

// Fused: gates GEMM (bf16 MFMA, fp32 weights converted on the fly) + bias + LSTM cell.
// Block: 256 thr = 4 waves. Tile: M=256 (full batch) x N=64 (4 gates x 16 j), K-step 32.
// Wave w owns rows [64w, 64w+64); n-tile nt == gate nt. So i,f,g,o for one (b,jj)
// sit in the same lane/reg across acc[mt][0..3] -> epilogue needs no data movement.
__global__ __launch_bounds__(256, 2) void lstm_gates_kernel(
    const float* __restrict__ x,   const float* __restrict__ h0,
    const float* __restrict__ c0,
    const float* __restrict__ Wih, const float* __restrict__ Whh,
    const float* __restrict__ bih, const float* __restrict__ bhh,
    float* __restrict__ outH, float* __restrict__ outC)
{
  __shared__ __align__(16) unsigned short As[B_DIM * LDA]; // 256 rows x 32 k (pad->40)
  __shared__ __align__(16) unsigned short Bs[64 * LDA];    // 64 rows x 32 k

  const int t   = threadIdx.x;
  const int j0  = blockIdx.x * 16;
  const int w   = t >> 6;        // wave id
  const int l   = t & 63;        // lane
  const int q   = l >> 4;        // quad
  const int col = l & 15;        // MFMA m/n index
  const int jj  = j0 + col;

  // --- staging indices ---
  // A: 4 chunks/thread; chunk rep: row = rep*64 + (t>>2), k8 = (t&3)*8 (8 contiguous floats)
  const int arow = t >> 2;
  const int k8   = (t & 3) * 8;
  // B: one chunk/thread; LDS row n_local = t>>2 = gate*16 + jl
  const int nloc = t >> 2;
  const int gate = nloc >> 4;
  const int jl   = nloc & 15;
  const long wrowg = (long)gate * H_DIM + j0 + jl;   // W_ih/W_hh row index

  long offAx[4], offAh[4];
  #pragma unroll
  for (int rep = 0; rep < 4; ++rep){
    int row = rep * 64 + arow;
    offAx[rep] = (long)row * K_X   + k8;
    offAh[rep] = (long)row * H_DIM + k8;
  }
  const long offBx = wrowg * K_X   + k8;
  const long offBh = wrowg * H_DIM + k8;

  // accumulators init = bias (same for all rows of a column)
  floatx4 acc[4][4];
  #pragma unroll
  for (int nt = 0; nt < 4; ++nt){
    float bsum = bih[nt * H_DIM + jj] + bhh[nt * H_DIM + jj];
    floatx4 v = {bsum, bsum, bsum, bsum};
    #pragma unroll
    for (int mt = 0; mt < 4; ++mt) acc[mt][nt] = v;
  }

  floatx4 pa[4][2];
  floatx4 pb[2];

  auto load_tile = [&](int ko){
    if (ko < K_X){
      #pragma unroll
      for (int rep = 0; rep < 4; ++rep){
        const float* p = x + offAx[rep] + ko;
        pa[rep][0] = *(const floatx4*)p;
        pa[rep][1] = *(const floatx4*)(p + 4);
      }
      const float* pB = Wih + offBx + ko;
      pb[0] = *(const floatx4*)pB;
      pb[1] = *(const floatx4*)(pB + 4);
    } else {
      const int kh = ko - K_X;
      #pragma unroll
      for (int rep = 0; rep < 4; ++rep){
        const float* p = h0 + offAh[rep] + kh;
        pa[rep][0] = *(const floatx4*)p;
        pa[rep][1] = *(const floatx4*)(p + 4);
      }
      const float* pB = Whh + offBh + kh;
      pb[0] = *(const floatx4*)pB;
      pb[1] = *(const floatx4*)(pB + 4);
    }
  };

  load_tile(0);

  const int wrow = w * 64;
  const int aoff = (wrow + col) * LDA + q * 8;
  const int boff = col * LDA + q * 8;

  for (int kt = 0; kt < NSTEP; ++kt){
    __syncthreads();
    // regs -> LDS (convert fp32 -> bf16)
    #pragma unroll
    for (int rep = 0; rep < 4; ++rep){
      uint4 wv;
      wv.x = pkbf(pa[rep][0].x, pa[rep][0].y);
      wv.y = pkbf(pa[rep][0].z, pa[rep][0].w);
      wv.z = pkbf(pa[rep][1].x, pa[rep][1].y);
      wv.w = pkbf(pa[rep][1].z, pa[rep][1].w);
      *(uint4*)&As[(rep * 64 + arow) * LDA + k8] = wv;
    }
    {
      uint4 wv;
      wv.x = pkbf(pb[0].x, pb[0].y);
      wv.y = pkbf(pb[0].z, pb[0].w);
      wv.z = pkbf(pb[1].x, pb[1].y);
      wv.w = pkbf(pb[1].z, pb[1].w);
      *(uint4*)&Bs[nloc * LDA + k8] = wv;
    }
    __syncthreads();

    if (kt + 1 < NSTEP) load_tile((kt + 1) * KT);  // prefetch next tile into regs

    short8 af[4], bf[4];
    #pragma unroll
    for (int mt = 0; mt < 4; ++mt)
      af[mt] = *(const short8*)&As[aoff + mt * 16 * LDA];
    #pragma unroll
    for (int nt = 0; nt < 4; ++nt)
      bf[nt] = *(const short8*)&Bs[boff + nt * 16 * LDA];
    #pragma unroll
    for (int mt = 0; mt < 4; ++mt)
      #pragma unroll
      for (int nt = 0; nt < 4; ++nt)
        acc[mt][nt] = __builtin_amdgcn_mfma_f32_16x16x32_bf16(af[mt], bf[nt], acc[mt][nt], 0, 0, 0);
  }

  // fused LSTM epilogue: D row = q*4 + r (within 16-tile), col = lane&15
  #pragma unroll
  for (int mt = 0; mt < 4; ++mt){
    #pragma unroll
    for (int r = 0; r < 4; ++r){
      int brow = wrow + mt * 16 + q * 4 + r;
      float iv = acc[mt][0][r];
      float fv = acc[mt][1][r];
      float gv = acc[mt][2][r];
      float ov = acc[mt][3][r];
      float cp = c0[(long)brow * H_DIM + jj];
      float cn = sigm(fv) * cp + sigm(iv) * tanh_fast(gv);
      float hn = sigm(ov) * tanh_fast(cn);
      outH[(long)brow * H_DIM + jj] = hn;
      outC[(long)brow * H_DIM + jj] = cn;
    }
  }
}

// y[b,o] = x[b].W0[o] + sum_r dw1[b,o,r]*z[b,r] + db[b,o] + b0[o],  z[b,r] = dw2[b,r].x[b]
// One block per batch row b; 4 waves; wave-level shuffle reductions; W0 reads coalesced.
__global__ __launch_bounds__(256) void y_kernel(
    const float* __restrict__ x, const float* __restrict__ hnew,
    const float* __restrict__ W0, const float* __restrict__ b0,
    float* __restrict__ y)
{
  __shared__ float xs[512];
  __shared__ float zs[4];
  const int b = blockIdx.x;
  const int t = threadIdx.x;
  const int w = t >> 6;
  const int l = t & 63;

  const float* xrow = x + (long)b * 512;
  xs[t]       = xrow[t];
  xs[t + 256] = xrow[t + 256];
  __syncthreads();

  const float* hrow = hnew + (long)b * H_DIM;

  // z[w] = dot(dw2[b,w,:], x[b,:]) ; dw2[b,r,i] = h_new[b, 2048 + r*512 + i]
  {
    const float* d2 = hrow + 2048 + w * 512;
    float p = 0.f;
    #pragma unroll
    for (int j = 0; j < 8; ++j)
      p += d2[l + 64 * j] * xs[l + 64 * j];
    #pragma unroll
    for (int off = 32; off > 0; off >>= 1)
      p += __shfl_down(p, off);
    if (l == 0) zs[w] = p;
  }
  __syncthreads();
  const float z0 = zs[0], z1 = zs[1], z2 = zs[2], z3 = zs[3];

  // each wave produces 128 outputs via full-row coalesced dot + butterfly reduce
  for (int oo = 0; oo < 128; ++oo){
    int o = w * 128 + oo;
    const float* wr = W0 + (long)o * 512;
    float p = 0.f;
    #pragma unroll
    for (int j = 0; j < 8; ++j)
      p += wr[l + 64 * j] * xs[l + 64 * j];
    #pragma unroll
    for (int off = 32; off > 0; off >>= 1)
      p += __shfl_down(p, off);
    if (l == 0){
      float4 d1 = *(const float4*)&hrow[o * 4];   // dw1[b,o,0..3]
      float r = p + b0[o] + hrow[4096 + o]
              + d1.x * z0 + d1.y * z1 + d1.z * z2 + d1.w * z3;
      y[(long)b * 512 + o] = r;
    }
  }
}

extern "C" void kernel_launch(void* const* d_in, const int* in_sizes, int n_in,
                              void* d_out, int out_size, void* d_ws, size_t ws_size,
                              hipStream_t stream)
{
  const float* x   = (const float*)d_in[0];
  const float* h0  = (const float*)d_in[1];
  const float* c0  = (const float*)d_in[2];
  const float* Wih = (const float*)d_in[3];
  const float* Whh = (const float*)d_in[4];
  const float* bih = (const float*)d_in[5];
  const float* bhh = (const float*)d_in[6];
  const float* W0  = (const float*)d_in[7];
  const float* b0  = (const float*)d_in[8];

  float* out  = (float*)d_out;
  float* y    = out;                       // 256*512
  float* outH = out + 131072;              // 256*4608
  float* outC = out + 131072 + 1179648;    // 256*4608

  hipLaunchKernelGGL(lstm_gates_kernel, dim3(288), dim3(256), 0, stream,
                     x, h0, c0, Wih, Whh, bih, bhh, outH, outC);
  hipLaunchKernelGGL(y_kernel, dim3(256), dim3(256), 0, stream,
                     x, outH, W0, b0, y);
}